// Round 1
// baseline (33.166 us; speedup 1.0000x reference)
//
#include <hip/hip_runtime.h>
#include <math.h>

#define IM 128

// K1: per (b, col) block, thread i computes frequency-i of the 1-D DFT of the
// complex column img[b, :, col], then magnitude * (1/128).
// mag layout: [b][i][col]  (b*16384 + i*128 + col)
__global__ void dft_mag_kernel(const float* __restrict__ x, float* __restrict__ mag) {
    const int blk = blockIdx.x;       // b*128 + col
    const int b   = blk >> 7;
    const int col = blk & 127;
    const int i   = threadIdx.x;      // output frequency

    __shared__ float re_s[IM], im_s[IM], twc[IM], tws[IM];

    const float* xr = x + (size_t)(b * 3 + 0) * IM * IM;
    const float* xi = x + (size_t)(b * 3 + 1) * IM * IM;
    re_s[i] = xr[i * IM + col];
    im_s[i] = xi[i * IM + col];
    const float ang = (float)(2.0 * M_PI / IM) * (float)i;
    twc[i] = cosf(ang);
    tws[i] = sinf(ang);
    __syncthreads();

    float ar = 0.f, ai = 0.f;
    #pragma unroll 8
    for (int y = 0; y < IM; ++y) {
        const int k  = (i * y) & 127;        // theta = 2*pi*k/128
        const float c = twc[k];
        const float s = tws[k];
        const float r = re_s[y];
        const float m = im_s[y];
        // (r + i m) * (c - i s)
        ar = fmaf(r, c, fmaf(m, s, ar));
        ai = fmaf(m, c, fmaf(-r, s, ai));
    }
    mag[((size_t)b * IM + i) * IM + col] = sqrtf(fmaf(ar, ar, ai * ai)) * (1.0f / IM);
}

// K2: E[b,o,w] = lrelu( sum_i conv_w[o,i] * mag[b,i,w] )
// block = (b*128 + o), thread = w (coalesced over w each i-step).
__global__ void conv_lrelu_kernel(const float* __restrict__ mag,
                                  const float* __restrict__ cw,
                                  float* __restrict__ E) {
    const int blk = blockIdx.x;       // b*128 + o
    const int b = blk >> 7;
    const int o = blk & 127;
    const int w = threadIdx.x;
    const float* magb = mag + (size_t)b * IM * IM;
    const float* cwo  = cw + (size_t)o * IM;
    float acc = 0.f;
    #pragma unroll 8
    for (int i = 0; i < IM; ++i) {
        acc = fmaf(cwo[i], magb[i * IM + w], acc);
    }
    acc = acc >= 0.f ? acc : 0.2f * acc;
    E[((size_t)b * IM + o) * IM + w] = acc;
}

// K3: broadcast E over h into out[b,o,h,w] (o<128), passthrough x[:,2] at o=128.
// One float4 per thread; fully coalesced 16B stores.
__global__ void bcast_kernel(const float4* __restrict__ E4,
                             const float4* __restrict__ x4,
                             float4* __restrict__ out4,
                             int total) {
    const int idx = blockIdx.x * blockDim.x + threadIdx.x;
    if (idx >= total) return;
    const int w4   = idx & 31;          // 128 floats = 32 float4 per row
    const int h    = (idx >> 5) & 127;
    const int rest = idx >> 12;         // b*129 + o
    const int o    = rest % 129;
    const int b    = rest / 129;
    float4 v;
    if (o < 128) {
        v = E4[(size_t)(b * 128 + o) * 32 + w4];
    } else {
        v = x4[((size_t)(b * 3 + 2) * 128 + h) * 32 + w4];
    }
    out4[idx] = v;
}

extern "C" void kernel_launch(void* const* d_in, const int* in_sizes, int n_in,
                              void* d_out, int out_size, void* d_ws, size_t ws_size,
                              hipStream_t stream) {
    const float* x  = (const float*)d_in[0];
    // d_in[1] = mask, unused by the reference forward
    const float* cw = (const float*)d_in[2];
    float* out = (float*)d_out;

    float* mag = (float*)d_ws;                 // 8*128*128 floats = 512 KB
    float* E   = mag + 8 * IM * IM;            // 8*128*128 floats = 512 KB

    dft_mag_kernel<<<8 * IM, IM, 0, stream>>>(x, mag);
    conv_lrelu_kernel<<<8 * IM, IM, 0, stream>>>(mag, cw, E);

    const int total_f4 = out_size / 4;         // 8*129*128*128 / 4 = 4,227,072
    bcast_kernel<<<(total_f4 + 255) / 256, 256, 0, stream>>>(
        (const float4*)E, (const float4*)x, (float4*)out, total_f4);
}

// Round 2
// 30.027 us; speedup vs baseline: 1.1046x; 1.1046x over previous
//
#include <hip/hip_runtime.h>
#include <math.h>

#define IM 128

// Fused K1+K2: per (b, col) block of 128 threads.
// Phase 1: thread i computes frequency-i of the 1-D column DFT of
//          img[b, :, col] via an incremental rotor (no twiddle table),
//          reading the column data as a single float2 LDS broadcast per step.
// Phase 2: thread o computes E[b,o,col] = lrelu( sum_i cw[o,i]*mag[i] )
//          with cw row streamed as float4 and mag broadcast from LDS.
__global__ __launch_bounds__(IM) void dft_conv_kernel(const float* __restrict__ x,
                                                      const float* __restrict__ cw,
                                                      float* __restrict__ E) {
    const int blk = blockIdx.x;       // b*128 + col
    const int b   = blk >> 7;
    const int col = blk & 127;
    const int tid = threadIdx.x;

    __shared__ float2 data_s[IM];
    __shared__ float  mag_s[IM];

    const float* xr = x + (size_t)(b * 3 + 0) * IM * IM;
    const float* xi = x + (size_t)(b * 3 + 1) * IM * IM;
    float2 d;
    d.x = xr[tid * IM + col];
    d.y = xi[tid * IM + col];
    data_s[tid] = d;

    // rotor for e^{-j*2*pi*tid*y/128}: step multiplier (cb, sb)
    const float ang = (float)(2.0 * M_PI / IM) * (float)tid;
    float sn, cb;
    __sincosf(ang, &sn, &cb);
    const float sb = -sn;

    __syncthreads();

    float c = 1.f, s = 0.f, ar = 0.f, ai = 0.f;
    #pragma unroll 8
    for (int y = 0; y < IM; ++y) {
        const float2 v = data_s[y];
        // accumulate (v.x + j v.y) * (c + j s)
        ar = fmaf(v.x, c, fmaf(-v.y, s, ar));
        ai = fmaf(v.y, c, fmaf( v.x, s, ai));
        // rotor step: (c,s) *= (cb,sb)
        const float t0 = s * sb;
        const float t1 = c * sb;
        c = fmaf(c, cb, -t0);
        s = fmaf(s, cb,  t1);
    }
    mag_s[tid] = sqrtf(fmaf(ar, ar, ai * ai)) * (1.0f / IM);

    __syncthreads();

    // Phase 2: matvec with cw row `tid`
    const float4* cwo = (const float4*)(cw + (size_t)tid * IM);
    float acc = 0.f;
    #pragma unroll 8
    for (int g = 0; g < IM / 4; ++g) {
        const float4 wv = cwo[g];
        acc = fmaf(wv.x, mag_s[4 * g + 0], acc);
        acc = fmaf(wv.y, mag_s[4 * g + 1], acc);
        acc = fmaf(wv.z, mag_s[4 * g + 2], acc);
        acc = fmaf(wv.w, mag_s[4 * g + 3], acc);
    }
    acc = acc >= 0.f ? acc : 0.2f * acc;
    E[((size_t)b * IM + tid) * IM + col] = acc;
}

// K3: broadcast E over h into out[b,o,h,w] (o<128), passthrough x[:,2] at o=128.
__global__ void bcast_kernel(const float4* __restrict__ E4,
                             const float4* __restrict__ x4,
                             float4* __restrict__ out4,
                             int total) {
    const int idx = blockIdx.x * blockDim.x + threadIdx.x;
    if (idx >= total) return;
    const int w4   = idx & 31;          // 128 floats = 32 float4 per row
    const int h    = (idx >> 5) & 127;
    const int rest = idx >> 12;         // b*129 + o
    const int o    = rest % 129;
    const int b    = rest / 129;
    float4 v;
    if (o < 128) {
        v = E4[(size_t)(b * 128 + o) * 32 + w4];
    } else {
        v = x4[((size_t)(b * 3 + 2) * 128 + h) * 32 + w4];
    }
    out4[idx] = v;
}

extern "C" void kernel_launch(void* const* d_in, const int* in_sizes, int n_in,
                              void* d_out, int out_size, void* d_ws, size_t ws_size,
                              hipStream_t stream) {
    const float* x  = (const float*)d_in[0];
    // d_in[1] = mask, unused by the reference forward
    const float* cw = (const float*)d_in[2];
    float* out = (float*)d_out;

    float* E = (float*)d_ws;                   // 8*128*128 floats = 512 KB

    dft_conv_kernel<<<8 * IM, IM, 0, stream>>>(x, cw, E);

    const int total_f4 = out_size / 4;         // 8*129*128*128 / 4 = 4,227,072
    bcast_kernel<<<(total_f4 + 255) / 256, 256, 0, stream>>>(
        (const float4*)E, (const float4*)x, (float4*)out, total_f4);
}